// Round 15
// baseline (1176.768 us; speedup 1.0000x reference)
//
#include <hip/hip_runtime.h>
#include <stdint.h>

typedef short short8 __attribute__((ext_vector_type(8)));
typedef unsigned short u16x4 __attribute__((ext_vector_type(4)));
typedef float floatx16 __attribute__((ext_vector_type(16)));

#define NPTS 16384
#define TILE_M 64
#define THREADS 1024
#define PA 2   // A-fragment (LDS) prefetch depth
#define PB 4   // B-fragment prefetch depth (single stream)

// f32 -> bf16 RNE via hardware cvt; bit-identical to add-round-shift.
__device__ inline unsigned short f2bf(float f) {
  __bf16 h = (__bf16)f;
  return __builtin_bit_cast(unsigned short, h);
}
__device__ inline float bf2f(unsigned short h) {
  union { unsigned u; float f; } v; v.u = ((unsigned)h) << 16;
  return v.f;
}

// De-convoy stagger (round 10: -30 us).
__device__ inline void wave_stagger(int wid) {
  int steps = ((wid >> 2) & 3) * 4 + (wid & 3);
  for (int d = 0; d < steps; ++d)
    asm volatile("s_nop 7\n\ts_nop 7\n\ts_nop 7\n\ts_nop 7\n\ts_nop 7" :::);
}

// Persistent NODE integrator: 1024 threads (16 waves), TILE_M=64, 256 WGs ->
// 4 waves/SIMD. Double-buffered act, same-B k-loop, swapped-operand MFMA
// (D^T: reg -> column, lane -> point).
// Fused flow projection (round-14 concept, DESPILLED):
//  - row-split: project acc0's row-half fully (3 sums) before touching acc1
//  - #pragma unroll 1 on the g-loop: kills the hoisted mega-live-range
//  - W4 + bias read from GLOBAL (6 KB, L1-resident broadcast) on the idle
//    VMEM pipe instead of the contended LDS port; w4t staging deleted.
// Numerics: h via bf16 round-trip = bit-identical values; summation reorder
// already validated (round 14 passed absmax 0.0078125).
__global__
__attribute__((amdgpu_flat_work_group_size(THREADS, THREADS),
               amdgpu_waves_per_eu(4, 4)))
void node_kernel(
    const float* __restrict__ x, float* __restrict__ outp,
    const unsigned short* __restrict__ wbf, const float* __restrict__ sfall,
    const float* __restrict__ w1a, const float* __restrict__ b1a,
    const float* __restrict__ b2a, const float* __restrict__ b3a,
    const float* __restrict__ w4a, const float* __restrict__ b4a,
    const float* __restrict__ w1b, const float* __restrict__ b1b,
    const float* __restrict__ b2b, const float* __restrict__ b3b,
    const float* __restrict__ w4b, const float* __restrict__ b4b)
{
  // each act buffer: 64 x 512 bf16, row pitch 520 u16 (1040 B = 65*16B ->
  // afrag b128 reads land row r on bank-quad r%8 => conflict-free). 65 KB x2.
  __shared__ unsigned short actA[TILE_M][520];
  __shared__ unsigned short actB2[TILE_M][520];
  __shared__ float pcur4[TILE_M][4];  // integrated position (float4 padded)
  __shared__ float pev4[TILE_M][4];   // stage evaluation point
  __shared__ float kac4[TILE_M][4];   // RK4 accumulator
  __shared__ float part[TILE_M][49];  // flow partials, odd pitch 49 dwords

  const int tid = threadIdx.x;
  const int wg = blockIdx.x;
  const int m0 = wg * TILE_M;
  const int batch = wg >> 6;          // 64 WGs per batch (4096/64)
  const int lane = tid & 63;
  const int wid = tid >> 6;           // 0..15: owns cols [wid*32, wid*32+32)

  // ---- init state from x ----
  if (tid < TILE_M * 3) {
    int m = tid / 3, c = tid % 3;
    float v = x[m0 * 3 + tid];
    pcur4[m][c] = v;
    pev4[m][c] = v;
  }
  __syncthreads();

  // act frag (B-operand): lane holds buf[rb*32+(lane&31)][kt*16+(lane>>5)*8..+8]
  // W frag (A-operand): fragment-major wf[((kt*16 + nt)*64 + lane)*8], nt = wid
  const int aBase = (lane & 31) * 1040 + (lane >> 5) * 16;   // bytes
  const int bcol = wid * 64 + lane;                          // short8 index

  // phase-1 column owned by this thread (2 threads per column, split rows)
  const int p1col = tid & 511;
  const int p1r0 = (tid >> 9) * 32;

  // epilogue indices (swapped C/D layout): lane -> point row, reg -> column
  const int ep_m = lane & 31;
  const int ep_nb = wid * 32 + 4 * (lane >> 5);   // + 8*g + i

  const float dt = 0.05f;

  #pragma unroll 1
  for (int f = 0; f < 2; ++f) {
    const float* w1 = f ? w1b : w1a;
    const float* b1v = f ? b1b : b1a;
    const float* b2v = f ? b2b : b2a;
    const float* b3v = f ? b3b : b3a;
    const float* w4 = f ? w4b : w4a;
    const float* b4v = f ? b4b : b4a;
    const short8* w2p = (const short8*)(wbf + (size_t)(f * 2 + 0) * 262144) + bcol;
    const short8* w3p = (const short8*)(wbf + (size_t)(f * 2 + 1) * 262144) + bcol;

    // hoisted per-block-f phase-1 constants
    const float ww0 = w1[p1col * 3 + 0], ww1 = w1[p1col * 3 + 1], ww2 = w1[p1col * 3 + 2];
    const float bb = b1v[p1col];
    const float ss = sfall[f * 2048 + batch * 512 + p1col];
    const float b40 = b4v[0], b41 = b4v[1], b42 = b4v[2];

    #pragma unroll 1
    for (int st = 0; st < 4; ++st) {
      #pragma unroll 1
      for (int stage = 0; stage < 4; ++stage) {
        // issue s=0 B prefetch before phase 1: restart the L2 weight stream
        // while the VALU phase runs (no dependency on act)
        short8 bq[PB];
        #pragma unroll
        for (int i = 0; i < PB - 1; ++i) bq[i] = w2p[i * 1024];

        // ---- phase 1: actA = relu(pev@W1.T + b1) * sf ----
        #pragma unroll 4
        for (int mi = 0; mi < 32; ++mi) {
          int m = p1r0 + mi;
          const float4 pv = *(const float4*)&pev4[m][0];
          float v = fmaf(pv.x, ww0, fmaf(pv.y, ww1, fmaf(pv.z, ww2, bb)));
          v = fmaxf(v, 0.f) * ss;
          actA[m][p1col] = f2bf(v);
        }
        __syncthreads();   // (1) actA complete before GEMM1 reads it

        // ======== GEMM1: h1 = relu(actA@W2.T + b2) + actA -> actB2 ========
        {
          const float* bias = b2v;
          const char* kb = (const char*)&actA[0][0];
          wave_stagger(wid);
          floatx16 acc0{}, acc1{};
          short8 aq0[PA], aq1[PA];
          #pragma unroll
          for (int i = 0; i < PA - 1; ++i) {
            aq0[i] = *(const short8*)(kb + aBase + i * 32);
            aq1[i] = *(const short8*)(kb + aBase + 33280 + i * 32);
          }
          #pragma unroll
          for (int kt = 0; kt < 32; ++kt) {
            int la = kt + PA - 1;
            if (la < 32) {
              aq0[la % PA] = *(const short8*)(kb + aBase + la * 32);
              aq1[la % PA] = *(const short8*)(kb + aBase + 33280 + la * 32);
            }
            int lb = kt + PB - 1;
            if (lb < 32) bq[lb % PB] = w2p[lb * 1024];
            __builtin_amdgcn_s_setprio(1);
            acc0 = __builtin_amdgcn_mfma_f32_32x32x16_bf16(bq[kt % PB], aq0[kt % PA], acc0, 0, 0, 0);
            acc1 = __builtin_amdgcn_mfma_f32_32x32x16_bf16(bq[kt % PB], aq1[kt % PA], acc1, 0, 0, 0);
            __builtin_amdgcn_s_setprio(0);
          }
          // restart W3 stream: L2 latency hides under the epilogue below
          #pragma unroll
          for (int i = 0; i < PB - 1; ++i) bq[i] = w3p[i * 1024];

          // epilogue 1: contiguous b64 residual RMW into actB2 (no barrier:
          // writes the buffer no k-loop is reading)
          #pragma unroll
          for (int g = 0; g < 4; ++g) {
            int n0 = ep_nb + 8 * g;
            const float4 bs = *(const float4*)&bias[n0];
            u16x4 r0 = *(const u16x4*)&actA[ep_m][n0];
            u16x4 r1 = *(const u16x4*)&actA[32 + ep_m][n0];
            u16x4 o0, o1;
            #pragma unroll
            for (int i = 0; i < 4; ++i) {
              float v = fmaxf(acc0[g * 4 + i] + ((const float*)&bs)[i], 0.f)
                        + bf2f((unsigned short)r0[i]);
              o0[i] = f2bf(v);
              v = fmaxf(acc1[g * 4 + i] + ((const float*)&bs)[i], 0.f)
                  + bf2f((unsigned short)r1[i]);
              o1[i] = f2bf(v);
            }
            *(u16x4*)&actB2[ep_m][n0] = o0;
            *(u16x4*)&actB2[32 + ep_m][n0] = o1;
          }
        }
        __syncthreads();   // (2) actB2 complete before GEMM2 reads it

        // ======== GEMM2 + fused flow projection (no LDS h write, no p4) ====
        {
          const float* bias = b3v;
          const char* kb = (const char*)&actB2[0][0];
          wave_stagger(wid);
          floatx16 acc0{}, acc1{};
          short8 aq0[PA], aq1[PA];
          #pragma unroll
          for (int i = 0; i < PA - 1; ++i) {
            aq0[i] = *(const short8*)(kb + aBase + i * 32);
            aq1[i] = *(const short8*)(kb + aBase + 33280 + i * 32);
          }
          #pragma unroll
          for (int kt = 0; kt < 32; ++kt) {
            int la = kt + PA - 1;
            if (la < 32) {
              aq0[la % PA] = *(const short8*)(kb + aBase + la * 32);
              aq1[la % PA] = *(const short8*)(kb + aBase + 33280 + la * 32);
            }
            int lb = kt + PB - 1;
            if (lb < 32) bq[lb % PB] = w3p[lb * 1024];
            __builtin_amdgcn_s_setprio(1);
            acc0 = __builtin_amdgcn_mfma_f32_32x32x16_bf16(bq[kt % PB], aq0[kt % PA], acc0, 0, 0, 0);
            acc1 = __builtin_amdgcn_mfma_f32_32x32x16_bf16(bq[kt % PB], aq1[kt % PA], acc1, 0, 0, 0);
            __builtin_amdgcn_s_setprio(0);
          }

          // ---- fused projection, row-half 0 (points ep_m, acc0) ----
          {
            float s0 = 0.f, s1 = 0.f, s2 = 0.f;
            #pragma unroll 1
            for (int g = 0; g < 4; ++g) {
              int n0 = ep_nb + 8 * g;
              const float4 bs = *(const float4*)&bias[n0];
              u16x4 r0 = *(const u16x4*)&actB2[ep_m][n0];
              float h[4];
              #pragma unroll
              for (int i = 0; i < 4; ++i) {
                float v = fmaxf(acc0[g * 4 + i] + ((const float*)&bs)[i], 0.f)
                          + bf2f((unsigned short)r0[i]);
                h[i] = bf2f(f2bf(v));
              }
              const float4 wv0 = *(const float4*)&w4[n0];          // L1 broadcast
              const float4 wv1 = *(const float4*)&w4[512 + n0];
              const float4 wv2 = *(const float4*)&w4[1024 + n0];
              #pragma unroll
              for (int i = 0; i < 4; ++i) {
                s0 = fmaf(h[i], ((const float*)&wv0)[i], s0);
                s1 = fmaf(h[i], ((const float*)&wv1)[i], s1);
                s2 = fmaf(h[i], ((const float*)&wv2)[i], s2);
              }
            }
            s0 += __shfl_xor(s0, 32);
            s1 += __shfl_xor(s1, 32);
            s2 += __shfl_xor(s2, 32);
            if (lane < 32) {
              part[ep_m][wid * 3 + 0] = s0;
              part[ep_m][wid * 3 + 1] = s1;
              part[ep_m][wid * 3 + 2] = s2;
            }
          }
          // ---- fused projection, row-half 1 (points 32+ep_m, acc1) ----
          {
            float s0 = 0.f, s1 = 0.f, s2 = 0.f;
            #pragma unroll 1
            for (int g = 0; g < 4; ++g) {
              int n0 = ep_nb + 8 * g;
              const float4 bs = *(const float4*)&bias[n0];
              u16x4 r1 = *(const u16x4*)&actB2[32 + ep_m][n0];
              float h[4];
              #pragma unroll
              for (int i = 0; i < 4; ++i) {
                float v = fmaxf(acc1[g * 4 + i] + ((const float*)&bs)[i], 0.f)
                          + bf2f((unsigned short)r1[i]);
                h[i] = bf2f(f2bf(v));
              }
              const float4 wv0 = *(const float4*)&w4[n0];
              const float4 wv1 = *(const float4*)&w4[512 + n0];
              const float4 wv2 = *(const float4*)&w4[1024 + n0];
              #pragma unroll
              for (int i = 0; i < 4; ++i) {
                s0 = fmaf(h[i], ((const float*)&wv0)[i], s0);
                s1 = fmaf(h[i], ((const float*)&wv1)[i], s1);
                s2 = fmaf(h[i], ((const float*)&wv2)[i], s2);
              }
            }
            s0 += __shfl_xor(s0, 32);
            s1 += __shfl_xor(s1, 32);
            s2 += __shfl_xor(s2, 32);
            if (lane < 32) {
              part[32 + ep_m][wid * 3 + 0] = s0;
              part[32 + ep_m][wid * 3 + 1] = s1;
              part[32 + ep_m][wid * 3 + 2] = s2;
            }
          }
        }
        __syncthreads();   // (3) partials complete before reduce

        // ---- reduce + tanh + RK4 stage update (192 threads) ----
        if (tid < TILE_M * 3) {
          int m = tid / 3, c = tid % 3;
          float sum = 0.f;
          #pragma unroll
          for (int w = 0; w < 16; ++w) sum += part[m][w * 3 + c];
          float bv = (c == 0) ? b40 : ((c == 1) ? b41 : b42);
          float fl = tanhf(sum + bv);
          float pc = pcur4[m][c];
          if (stage == 0) {
            kac4[m][c] = fl;
            pev4[m][c] = fmaf(0.5f * dt, fl, pc);
          } else if (stage == 1) {
            kac4[m][c] += 2.f * fl;
            pev4[m][c] = fmaf(0.5f * dt, fl, pc);
          } else if (stage == 2) {
            kac4[m][c] += 2.f * fl;
            pev4[m][c] = fmaf(dt, fl, pc);
          } else {
            float np = fmaf(dt / 6.f, kac4[m][c] + fl, pc);
            pcur4[m][c] = np;
            pev4[m][c] = np;
          }
        }
        __syncthreads();   // (4) pev consumers done before next p1
      }
    }
  }

  // ---- write final positions ----
  if (tid < TILE_M * 3) outp[m0 * 3 + tid] = pcur4[tid / 3][tid % 3];
}

// ---- setup: shuffle W (512x512 fp32 row-major, W[n][k]) into fragment-major
// bf16: dst[((kt*16 + nt)*64 + lane)*8 + j] = W[nt*32+(lane&31)][kt*16+(lane>>5)*8+j]
__global__ void setup_shuffle(const float* s0, const float* s1, const float* s2,
                              const float* s3, unsigned short* dst) {
  int idx = blockIdx.x * blockDim.x + threadIdx.x;   // 4 * 32768
  int w = idx >> 15;
  int r = idx & 32767;            // (kt*16+nt)*64 + lane
  int lane = r & 63;
  int tile = r >> 6;
  int nt = tile & 15, kt = tile >> 4;
  const float* W = (w == 0) ? s0 : (w == 1) ? s1 : (w == 2) ? s2 : s3;
  int n = nt * 32 + (lane & 31);
  int k0 = kt * 16 + (lane >> 5) * 8;
  const float* src = W + n * 512 + k0;
  unsigned short* d = dst + ((size_t)w << 18) + (size_t)r * 8;
  #pragma unroll
  for (int j = 0; j < 8; ++j) d[j] = f2bf(src[j]);
}

__global__ void setup_sf(const float* code, const float* cw1, const float* cb1,
                         const float* cw2, const float* cb2, float* sfout) {
  int f = blockIdx.x >> 2, b = blockIdx.x & 3;
  const float* cw = f ? cw2 : cw1;
  const float* cb = f ? cb2 : cb1;
  int j = threadIdx.x;
  const float* c = code + b * 512;
  float s = cb[j];
  for (int k = 0; k < 512; ++k) s = fmaf(c[k], cw[j * 512 + k], s);
  sfout[f * 2048 + b * 512 + j] = tanhf(s);
}

extern "C" void kernel_launch(void* const* d_in, const int* in_sizes, int n_in,
                              void* d_out, int out_size, void* d_ws, size_t ws_size,
                              hipStream_t stream) {
  const float* code = (const float*)d_in[0];
  const float* x    = (const float*)d_in[1];
  char* ws = (char*)d_ws;
  float* sf = (float*)ws;                               // 2*2048 fp32 = 16 KB
  unsigned short* wbf = (unsigned short*)(ws + 16384);  // 4 * 262144 u16 = 2 MB

  setup_shuffle<<<512, 256, 0, stream>>>((const float*)d_in[4], (const float*)d_in[6],
                                         (const float*)d_in[14], (const float*)d_in[16], wbf);
  setup_sf<<<8, 512, 0, stream>>>(code, (const float*)d_in[10], (const float*)d_in[11],
                                  (const float*)d_in[20], (const float*)d_in[21], sf);

  node_kernel<<<NPTS / TILE_M, THREADS, 0, stream>>>(x, (float*)d_out, wbf, sf,
      (const float*)d_in[2], (const float*)d_in[3], (const float*)d_in[5],
      (const float*)d_in[7], (const float*)d_in[8], (const float*)d_in[9],
      (const float*)d_in[12], (const float*)d_in[13], (const float*)d_in[15],
      (const float*)d_in[17], (const float*)d_in[18], (const float*)d_in[19]);
}

// Round 16
// 745.192 us; speedup vs baseline: 1.5791x; 1.5791x over previous
//
#include <hip/hip_runtime.h>
#include <stdint.h>

typedef short short8 __attribute__((ext_vector_type(8)));
typedef unsigned short u16x4 __attribute__((ext_vector_type(4)));
typedef float floatx16 __attribute__((ext_vector_type(16)));

#define NPTS 16384
#define TILE_M 64
#define THREADS 1024
#define PA 2   // A-fragment (LDS) prefetch depth
#define PB 4   // B-fragment prefetch depth (single stream)

// f32 -> bf16 RNE via hardware cvt; bit-identical to add-round-shift.
__device__ inline unsigned short f2bf(float f) {
  __bf16 h = (__bf16)f;
  return __builtin_bit_cast(unsigned short, h);
}
__device__ inline float bf2f(unsigned short h) {
  union { unsigned u; float f; } v; v.u = ((unsigned)h) << 16;
  return v.f;
}

// De-convoy stagger (round 10: -30 us).
__device__ inline void wave_stagger(int wid) {
  int steps = ((wid >> 2) & 3) * 4 + (wid & 3);
  for (int d = 0; d < steps; ++d)
    asm volatile("s_nop 7\n\ts_nop 7\n\ts_nop 7\n\ts_nop 7\n\ts_nop 7" :::);
}

// Persistent NODE integrator — round-13 champion configuration (691 us).
// 1024 threads (16 waves), TILE_M=64, 256 WGs -> 4 waves/SIMD.
// Double-buffered act (4 barriers/eval), same-B k-loop (2 A ds_read_b128 +
// 1 B global + 2 MFMA per kt per wave), swapped-operand MFMA
// (D^T: reg -> column, lane -> point) giving a contiguous-b64 epilogue.
// Rounds 14/15 (fused flow projection) both spilled: GEMM2 k-loop state
// alone saturates the 64-VGPR budget the 1024-thread allocator enforces;
// fusion needs ~+20 live regs -> scratch. Reverted.
__global__
__attribute__((amdgpu_flat_work_group_size(THREADS, THREADS),
               amdgpu_waves_per_eu(4, 4)))
void node_kernel(
    const float* __restrict__ x, float* __restrict__ outp,
    const unsigned short* __restrict__ wbf, const float* __restrict__ sfall,
    const float* __restrict__ w1a, const float* __restrict__ b1a,
    const float* __restrict__ b2a, const float* __restrict__ b3a,
    const float* __restrict__ w4a, const float* __restrict__ b4a,
    const float* __restrict__ w1b, const float* __restrict__ b1b,
    const float* __restrict__ b2b, const float* __restrict__ b3b,
    const float* __restrict__ w4b, const float* __restrict__ b4b)
{
  // each act buffer: 64 x 512 bf16, row pitch 520 u16 (1040 B = 65*16B ->
  // afrag b128 reads land row r on bank-quad r%8 => conflict-free). 65 KB x2.
  __shared__ unsigned short actA[TILE_M][520];
  __shared__ unsigned short actB2[TILE_M][520];
  __shared__ float pcur4[TILE_M][4];  // integrated position (float4 padded)
  __shared__ float pev4[TILE_M][4];   // stage evaluation point
  __shared__ float kac4[TILE_M][4];   // RK4 accumulator
  // W4 staged chunk-major: chunk q holds w4[n][q*8+e], pitch 28 floats ->
  // phase-4 float4 reads 2-way aliased (free). Verified: conflicts 14.7M->2.1M
  // on the w4 path.
  __shared__ float w4c[64][28];

  const int tid = threadIdx.x;
  const int wg = blockIdx.x;
  const int m0 = wg * TILE_M;
  const int batch = wg >> 6;          // 64 WGs per batch (4096/64)
  const int lane = tid & 63;
  const int wid = tid >> 6;           // 0..15: owns cols [wid*32, wid*32+32)

  // ---- init state from x ----
  if (tid < TILE_M * 3) {
    int m = tid / 3, c = tid % 3;
    float v = x[m0 * 3 + tid];
    pcur4[m][c] = v;
    pev4[m][c] = v;
  }
  __syncthreads();

  // act frag (B-operand): lane holds buf[rb*32+(lane&31)][kt*16+(lane>>5)*8..+8]
  // W frag (A-operand): fragment-major wf[((kt*16 + nt)*64 + lane)*8], nt = wid
  const int aBase = (lane & 31) * 1040 + (lane >> 5) * 16;   // bytes
  const int bcol = wid * 64 + lane;                          // short8 index

  // phase-1 column owned by this thread (2 threads per column, split rows)
  const int p1col = tid & 511;
  const int p1r0 = (tid >> 9) * 32;

  // epilogue indices (swapped C/D layout): lane -> point row, reg -> column
  const int ep_m = lane & 31;
  const int ep_nb = wid * 32 + 4 * (lane >> 5);   // + 8*g + i

  const float dt = 0.05f;

  #pragma unroll 1
  for (int f = 0; f < 2; ++f) {
    const float* w1 = f ? w1b : w1a;
    const float* b1v = f ? b1b : b1a;
    const float* b2v = f ? b2b : b2a;
    const float* b3v = f ? b3b : b3a;
    const float* w4 = f ? w4b : w4a;
    const float* b4v = f ? b4b : b4a;
    const short8* w2p = (const short8*)(wbf + (size_t)(f * 2 + 0) * 262144) + bcol;
    const short8* w3p = (const short8*)(wbf + (size_t)(f * 2 + 1) * 262144) + bcol;

    // hoisted per-block-f phase-1 constants
    const float ww0 = w1[p1col * 3 + 0], ww1 = w1[p1col * 3 + 1], ww2 = w1[p1col * 3 + 2];
    const float bb = b1v[p1col];
    const float ss = sfall[f * 2048 + batch * 512 + p1col];
    const float b40 = b4v[0], b41 = b4v[1], b42 = b4v[2];

    // stage W4 chunk-major into LDS once per f-block
    for (int i = tid; i < 64 * 24; i += THREADS) {
      int q = i / 24, r = i % 24;           // n = r/8, e = r%8
      w4c[q][r] = w4[(r >> 3) * 512 + q * 8 + (r & 7)];
    }
    __syncthreads();

    #pragma unroll 1
    for (int st = 0; st < 4; ++st) {
      #pragma unroll 1
      for (int stage = 0; stage < 4; ++stage) {
        // issue s=0 B prefetch before phase 1: restart the L2 weight stream
        // while the VALU phase runs (no dependency on act)
        short8 bq[PB];
        #pragma unroll
        for (int i = 0; i < PB - 1; ++i) bq[i] = w2p[i * 1024];

        // ---- phase 1: actA = relu(pev@W1.T + b1) * sf ----
        #pragma unroll 4
        for (int mi = 0; mi < 32; ++mi) {
          int m = p1r0 + mi;
          const float4 pv = *(const float4*)&pev4[m][0];
          float v = fmaf(pv.x, ww0, fmaf(pv.y, ww1, fmaf(pv.z, ww2, bb)));
          v = fmaxf(v, 0.f) * ss;
          actA[m][p1col] = f2bf(v);
        }
        __syncthreads();   // (1) actA complete before GEMM1 reads it

        // ---- phases 2+3: two residual GEMMs, h = relu(h@W.T + b) + h ----
        #pragma unroll 1
        for (int s = 0; s < 2; ++s) {
          const float* bias = s ? b3v : b2v;
          const short8* bp = s ? w3p : w2p;
          const char* kb = s ? (const char*)&actB2[0][0] : (const char*)&actA[0][0];

          wave_stagger(wid);   // de-convoy

          floatx16 acc0{}, acc1{};
          short8 aq0[PA], aq1[PA];
          #pragma unroll
          for (int i = 0; i < PA - 1; ++i) {
            aq0[i] = *(const short8*)(kb + aBase + i * 32);
            aq1[i] = *(const short8*)(kb + aBase + 33280 + i * 32);
          }

          #pragma unroll
          for (int kt = 0; kt < 32; ++kt) {
            int la = kt + PA - 1;
            if (la < 32) {
              aq0[la % PA] = *(const short8*)(kb + aBase + la * 32);
              aq1[la % PA] = *(const short8*)(kb + aBase + 33280 + la * 32);
            }
            int lb = kt + PB - 1;
            if (lb < 32) bq[lb % PB] = bp[lb * 1024];
            __builtin_amdgcn_s_setprio(1);
            // SWAPPED operands: D^T — reg -> column, lane -> point
            acc0 = __builtin_amdgcn_mfma_f32_32x32x16_bf16(bq[kt % PB], aq0[kt % PA], acc0, 0, 0, 0);
            acc1 = __builtin_amdgcn_mfma_f32_32x32x16_bf16(bq[kt % PB], aq1[kt % PA], acc1, 0, 0, 0);
            __builtin_amdgcn_s_setprio(0);
          }

          // restart the NEXT GEMM's B-stream (W3) now: L2 latency hides
          // under the epilogue below (no dependency on act)
          if (s == 0) {
            #pragma unroll
            for (int i = 0; i < PB - 1; ++i) bq[i] = w3p[i * 1024];
          }

          // epilogue (swapped layout): thread owns point rows ep_m, ep_m+32
          // and columns ep_nb + 8g + (0..3) — CONTIGUOUS 4-col groups ->
          // b64 residual reads/writes (8+8 slots vs 32+32 b16).
          // NO barrier: writes go to the buffer no k-loop is reading.
          {
            unsigned short (* __restrict__ wr)[520] = s ? actA : actB2;
            unsigned short (* __restrict__ rd)[520] = s ? actB2 : actA;
            #pragma unroll
            for (int g = 0; g < 4; ++g) {
              int n0 = ep_nb + 8 * g;
              const float4 bs = *(const float4*)&bias[n0];
              u16x4 r0 = *(const u16x4*)&rd[ep_m][n0];
              u16x4 r1 = *(const u16x4*)&rd[32 + ep_m][n0];
              u16x4 o0, o1;
              #pragma unroll
              for (int i = 0; i < 4; ++i) {
                float v = fmaxf(acc0[g * 4 + i] + ((const float*)&bs)[i], 0.f)
                          + bf2f((unsigned short)r0[i]);
                o0[i] = f2bf(v);
                v = fmaxf(acc1[g * 4 + i] + ((const float*)&bs)[i], 0.f)
                    + bf2f((unsigned short)r1[i]);
                o1[i] = f2bf(v);
              }
              *(u16x4*)&wr[ep_m][n0] = o0;
              *(u16x4*)&wr[32 + ep_m][n0] = o1;
            }
          }
          __syncthreads();   // (2)/(3) epilogue buffer complete before next reader
        }

        // ---- phase 4: flow = tanh(actA@W4.T + b4), then RK4 stage update ----
        // 16-lane groups per point; 4 chunks of short8 (b128 act reads);
        // W4 from chunk-major LDS (2-way aliased float4 reads = free)
        {
          int m = tid >> 4, jj = tid & 15;
          const unsigned short* arow = &actA[m][0];
          float s0 = 0.f, s1 = 0.f, s2 = 0.f;
          #pragma unroll
          for (int c = 0; c < 4; ++c) {
            int q = c * 16 + jj;
            int k0 = q * 8;
            short8 av = *(const short8*)(arow + k0);
            const float* wc = &w4c[q][0];
            #pragma unroll
            for (int half = 0; half < 2; ++half) {
              float4 wv0 = *(const float4*)(wc + 0 + half * 4);
              float4 wv1 = *(const float4*)(wc + 8 + half * 4);
              float4 wv2 = *(const float4*)(wc + 16 + half * 4);
              #pragma unroll
              for (int e = 0; e < 4; ++e) {
                float a = bf2f((unsigned short)av[half * 4 + e]);
                s0 = fmaf(a, ((const float*)&wv0)[e], s0);
                s1 = fmaf(a, ((const float*)&wv1)[e], s1);
                s2 = fmaf(a, ((const float*)&wv2)[e], s2);
              }
            }
          }
          s0 += __shfl_xor(s0, 1); s1 += __shfl_xor(s1, 1); s2 += __shfl_xor(s2, 1);
          s0 += __shfl_xor(s0, 2); s1 += __shfl_xor(s1, 2); s2 += __shfl_xor(s2, 2);
          s0 += __shfl_xor(s0, 4); s1 += __shfl_xor(s1, 4); s2 += __shfl_xor(s2, 4);
          s0 += __shfl_xor(s0, 8); s1 += __shfl_xor(s1, 8); s2 += __shfl_xor(s2, 8);
          if (jj < 3) {
            float sv = (jj == 0) ? s0 : ((jj == 1) ? s1 : s2);
            float bv = (jj == 0) ? b40 : ((jj == 1) ? b41 : b42);
            float fl = tanhf(sv + bv);
            float pc = pcur4[m][jj];
            if (stage == 0) {
              kac4[m][jj] = fl;
              pev4[m][jj] = fmaf(0.5f * dt, fl, pc);
            } else if (stage == 1) {
              kac4[m][jj] += 2.f * fl;
              pev4[m][jj] = fmaf(0.5f * dt, fl, pc);
            } else if (stage == 2) {
              kac4[m][jj] += 2.f * fl;
              pev4[m][jj] = fmaf(dt, fl, pc);
            } else {
              float np = fmaf(dt / 6.f, kac4[m][jj] + fl, pc);
              pcur4[m][jj] = np;
              pev4[m][jj] = np;
            }
          }
        }
        __syncthreads();   // (4) pev/actA consumers done before next p1
      }
    }
  }

  // ---- write final positions ----
  if (tid < TILE_M * 3) outp[m0 * 3 + tid] = pcur4[tid / 3][tid % 3];
}

// ---- setup: shuffle W (512x512 fp32 row-major, W[n][k]) into fragment-major
// bf16: dst[((kt*16 + nt)*64 + lane)*8 + j] = W[nt*32+(lane&31)][kt*16+(lane>>5)*8+j]
// (serves as the A-operand of the swapped MFMA — same element placement)
__global__ void setup_shuffle(const float* s0, const float* s1, const float* s2,
                              const float* s3, unsigned short* dst) {
  int idx = blockIdx.x * blockDim.x + threadIdx.x;   // 4 * 32768
  int w = idx >> 15;
  int r = idx & 32767;            // (kt*16+nt)*64 + lane
  int lane = r & 63;
  int tile = r >> 6;
  int nt = tile & 15, kt = tile >> 4;
  const float* W = (w == 0) ? s0 : (w == 1) ? s1 : (w == 2) ? s2 : s3;
  int n = nt * 32 + (lane & 31);
  int k0 = kt * 16 + (lane >> 5) * 8;
  const float* src = W + n * 512 + k0;
  unsigned short* d = dst + ((size_t)w << 18) + (size_t)r * 8;
  #pragma unroll
  for (int j = 0; j < 8; ++j) d[j] = f2bf(src[j]);
}

__global__ void setup_sf(const float* code, const float* cw1, const float* cb1,
                         const float* cw2, const float* cb2, float* sfout) {
  int f = blockIdx.x >> 2, b = blockIdx.x & 3;
  const float* cw = f ? cw2 : cw1;
  const float* cb = f ? cb2 : cb1;
  int j = threadIdx.x;
  const float* c = code + b * 512;
  float s = cb[j];
  for (int k = 0; k < 512; ++k) s = fmaf(c[k], cw[j * 512 + k], s);
  sfout[f * 2048 + b * 512 + j] = tanhf(s);
}

extern "C" void kernel_launch(void* const* d_in, const int* in_sizes, int n_in,
                              void* d_out, int out_size, void* d_ws, size_t ws_size,
                              hipStream_t stream) {
  const float* code = (const float*)d_in[0];
  const float* x    = (const float*)d_in[1];
  char* ws = (char*)d_ws;
  float* sf = (float*)ws;                               // 2*2048 fp32 = 16 KB
  unsigned short* wbf = (unsigned short*)(ws + 16384);  // 4 * 262144 u16 = 2 MB

  setup_shuffle<<<512, 256, 0, stream>>>((const float*)d_in[4], (const float*)d_in[6],
                                         (const float*)d_in[14], (const float*)d_in[16], wbf);
  setup_sf<<<8, 512, 0, stream>>>(code, (const float*)d_in[10], (const float*)d_in[11],
                                  (const float*)d_in[20], (const float*)d_in[21], sf);

  node_kernel<<<NPTS / TILE_M, THREADS, 0, stream>>>(x, (float*)d_out, wbf, sf,
      (const float*)d_in[2], (const float*)d_in[3], (const float*)d_in[5],
      (const float*)d_in[7], (const float*)d_in[8], (const float*)d_in[9],
      (const float*)d_in[12], (const float*)d_in[13], (const float*)d_in[15],
      (const float*)d_in[17], (const float*)d_in[18], (const float*)d_in[19]);
}